// Round 7
// baseline (226.218 us; speedup 1.0000x reference)
//
#include <hip/hip_runtime.h>
#include <math.h>

#define Bsz 128
#define Usz 16
#define Dsz 256
#define Nsz 1024
#define Osz 256
#define BK  64
#define LDT 72   // LDS row stride in u16 (144B); groups 0..7 used, 8 u16 pad

typedef __attribute__((ext_vector_type(2))) unsigned int u32x2;
typedef __attribute__((ext_vector_type(4))) unsigned int u32x4;
typedef __attribute__((ext_vector_type(4))) float f32x4;
typedef __attribute__((ext_vector_type(8))) short bf16x8;

union cell_u { u32x4 u; bf16x8 b; };

__device__ __forceinline__ unsigned int fbits(float f) {
    union { float f; unsigned int u; } v; v.f = f; return v.u;
}
// pack two f32 -> (bf16(hi)<<16)|bf16(lo) by truncation: 1 v_perm_b32
__device__ __forceinline__ unsigned int pk(float lo, float hi) {
    return __builtin_amdgcn_perm(fbits(hi), fbits(lo), 0x07060302u);
}
__device__ __forceinline__ unsigned short bf16t(float f) {
    return (unsigned short)(fbits(f) >> 16);
}

// ---------------- lr = softmax_u(X·alr / T) ----------------
__global__ __launch_bounds__(256)
void lr_kernel(const float* __restrict__ X, const float* __restrict__ alr,
               const float* __restrict__ temp, float* __restrict__ lr)
{
    const int b = blockIdx.x;
    const int t = threadIdx.x;
    const int u = t >> 4;
    const int l = t & 15;
    const f32x4* xp = (const f32x4*)(X + ((size_t)b * Usz + u) * Dsz + l * 16);
    const f32x4* ap = (const f32x4*)(alr + (size_t)u * Dsz + l * 16);
    float s = 0.f;
    #pragma unroll
    for (int j = 0; j < 4; j++) {
        const f32x4 xv = xp[j], av = ap[j];
        s += xv[0]*av[0] + xv[1]*av[1] + xv[2]*av[2] + xv[3]*av[3];
    }
    s += __shfl_down(s, 8, 16);
    s += __shfl_down(s, 4, 16);
    s += __shfl_down(s, 2, 16);
    s += __shfl_down(s, 1, 16);
    __shared__ float logits[16];
    if (l == 0) logits[u] = s;
    __syncthreads();
    if (t < 16) {
        const float T = temp[0];
        float m = -1e30f;
        #pragma unroll
        for (int i = 0; i < 16; i++) m = fmaxf(m, logits[i] / T);
        float sum = 0.f;
        #pragma unroll
        for (int i = 0; i < 16; i++) sum += expf(logits[i] / T - m);
        lr[(size_t)b * Usz + t] = expf(logits[t] / T - m) / sum;
    }
}

// ---- state GEMM v7: BARRIER-FREE wave-private design ----
// grid 512 = u16 x nt32, block = 128 thr = 2 independent waves.
// Wave wv owns rows wv*64..+63 (full M=128 per block -> B fetched ONCE
// chip-wide; v6's mt-split doubled FETCH 48->123MB). Each wave stages its
// OWN B tile (64k x 32n, bf16, XOR-swizzled) into its OWN LDS region:
// per-wave DS ops retire in order -> NO s_barrier anywhere. A is read
// direct-to-fragment from global (k-contiguous layout, L2-hot).
// B-write swizzle: k-group g stored at g ^ (n>>2) -> write banks provably
// conflict-free (c -> 16(c&1)+4(j^c) mod 32 injective); reads stay b128.
__global__ __launch_bounds__(128)
void state_gemm(const float* __restrict__ X, const float* __restrict__ state,
                const float* __restrict__ W, const float* __restrict__ Win,
                const float* __restrict__ bias, const float* __restrict__ sr,
                const float* __restrict__ lr, float* __restrict__ out0)
{
    const int id = blockIdx.x;        // 512 = u16 x nt32 (nt inner)
    const int nt = id & 31;
    const int u  = id >> 5;

    const int tid  = threadIdx.x;     // 0..127
    const int wv   = tid >> 6;        // wave index = m-half
    const int lane = tid & 63;
    const int l16  = lane & 15, kgl = lane >> 4;
    const int kL   = lane >> 3;       // 0..7  (B staging k-within-group)
    const int c    = lane & 7;        // B staging n-group
    const int nB   = 4 * c;
    const int col0 = nt * 32;
    const int m0   = wv * 64;

    __shared__ unsigned short Bs[2][2][32 * LDT];   // [wave][buf], 18.4 KB

    const float sru = sr[u];

    f32x4 rbE[8], rbO[8];   // B raw double-buffer (8 f32x4/lane = full tile)

    auto ldB = [&](int s, f32x4 (&rb)[8]) {
        const int k0 = s * BK;
        const float* bbase = (k0 < Dsz)
            ? Win + (size_t)u * Dsz * Nsz + (size_t)(k0 + kL) * Nsz + col0 + nB
            : W   + (size_t)u * Nsz * Nsz + (size_t)(k0 - Dsz + kL) * Nsz + col0 + nB;
        #pragma unroll
        for (int j = 0; j < 8; j++)
            rb[j] = *(const f32x4*)(bbase + (size_t)8 * j * Nsz);
    };
    // row n = nB+e (n>>2 == c), k = kL + 8j -> phys group = j ^ c
    auto wrB = [&](int p, f32x4 (&rb)[8], float sc) {
        unsigned short* bs = &Bs[wv][p][0];
        #pragma unroll
        for (int j = 0; j < 8; j++) {
            const int go = ((j ^ c) << 3) + kL;
            #pragma unroll
            for (int e = 0; e < 4; e++)
                bs[(nB + e) * LDT + go] = bf16t(rb[j][e] * sc);
        }
    };
    auto rdB = [&](int p, int ni, int kk) -> bf16x8 {
        const int n = ni * 16 + l16;
        const int go = ((kk * 4 + kgl) ^ (n >> 2)) << 3;
        return *(const bf16x8*)&Bs[wv][p][n * LDT + go];
    };
    auto ldAf = [&](int s, int mi, int kk) -> bf16x8 {
        const int k = s * BK + kk * 32 + kgl * 8;
        const int r = m0 + mi * 16 + l16;
        const float* ap = (k < Dsz)
            ? X     + ((size_t)r * Usz + u) * Dsz + k
            : state + ((size_t)r * Usz + u) * Nsz + (k - Dsz);
        const f32x4 a0 = *(const f32x4*)ap;
        const f32x4 a1 = *(const f32x4*)(ap + 4);
        cell_u af;
        af.u[0] = pk(a0[0], a0[1]); af.u[1] = pk(a0[2], a0[3]);
        af.u[2] = pk(a1[0], a1[1]); af.u[3] = pk(a1[2], a1[3]);
        return af.b;
    };

    f32x4 acc[4][2] = {};
    auto comp = [&](int s, int p) {
        #pragma unroll
        for (int kk = 0; kk < 2; kk++) {
            const bf16x8 bf0 = rdB(p, 0, kk);
            const bf16x8 bf1 = rdB(p, 1, kk);
            #pragma unroll
            for (int mi = 0; mi < 4; mi++) {
                const bf16x8 af = ldAf(s, mi, kk);
                acc[mi][0] = __builtin_amdgcn_mfma_f32_16x16x32_bf16(af, bf0, acc[mi][0], 0, 0, 0);
                acc[mi][1] = __builtin_amdgcn_mfma_f32_16x16x32_bf16(af, bf1, acc[mi][1], 0, 0, 0);
            }
        }
    };
    auto scB = [&](int s) -> float { return (s * BK < Dsz) ? 1.f : sru; };

    // prologue: raw B(0)->E, B(1)->O; stage step0
    ldB(0, rbE);
    ldB(1, rbO);
    wrB(0, rbE, scB(0));

    for (int s2 = 0; s2 < 10; s2++) {
        const int s = 2 * s2;
        if (s + 2 < 20) ldB(s + 2, rbE);
        wrB(1, rbO, scB(s + 1));
        comp(s, 0);
        if (s + 3 < 20) ldB(s + 3, rbO);
        if (s + 2 < 20) wrB(0, rbE, scB(s + 2));
        comp(s + 1, 1);
    }

    // C/D layout: col=lane&15, row=(lane>>4)*4+reg (HW-verified)
    #pragma unroll
    for (int ni = 0; ni < 2; ni++) {
        const int gcol = col0 + ni * 16 + l16;
        const float bi = bias[u * Nsz + gcol];
        #pragma unroll
        for (int mi = 0; mi < 4; mi++) {
            #pragma unroll
            for (int rg = 0; rg < 4; rg++) {
                const int grow = m0 + mi * 16 + kgl * 4 + rg;
                const size_t idx = ((size_t)grow * Usz + u) * Nsz + gcol;
                const float th = tanhf(acc[mi][ni][rg] + bi);
                const float lv = lr[grow * Usz + u];
                out0[idx] = (1.f - lv) * state[idx] + lv * th;
            }
        }
    }
}

// ---- out GEMM v7: same barrier-free structure, split-K ----
// grid = ks x u16 x ot8, block 128 thr = 2 waves (M=128, N=32), nsteps K/64.
__global__ __launch_bounds__(128)
void out_gemm(const float* __restrict__ ns, const float* __restrict__ Wout,
              float* __restrict__ dst, int nsteps, int partial)
{
    const int id = blockIdx.x;
    const int ot = id & 7;
    const int u  = (id >> 3) & 15;
    const int ks = id >> 7;
    const int kbase = ks * nsteps * BK;

    const int tid  = threadIdx.x;
    const int wv   = tid >> 6;
    const int lane = tid & 63;
    const int l16  = lane & 15, kgl = lane >> 4;
    const int kL   = lane >> 3;
    const int c    = lane & 7;
    const int nB   = 4 * c;
    const int col0 = ot * 32;
    const int m0   = wv * 64;

    __shared__ unsigned short Bs[2][2][32 * LDT];

    f32x4 rbE[8], rbO[8];

    auto ldB = [&](int s, f32x4 (&rb)[8]) {
        const float* bbase = Wout + (size_t)u * Nsz * Osz
                           + (size_t)(kbase + s * BK + kL) * Osz + col0 + nB;
        #pragma unroll
        for (int j = 0; j < 8; j++)
            rb[j] = *(const f32x4*)(bbase + (size_t)8 * j * Osz);
    };
    auto wrB = [&](int p, f32x4 (&rb)[8]) {
        unsigned short* bs = &Bs[wv][p][0];
        #pragma unroll
        for (int j = 0; j < 8; j++) {
            const int go = ((j ^ c) << 3) + kL;
            #pragma unroll
            for (int e = 0; e < 4; e++)
                bs[(nB + e) * LDT + go] = bf16t(rb[j][e]);
        }
    };
    auto rdB = [&](int p, int ni, int kk) -> bf16x8 {
        const int n = ni * 16 + l16;
        const int go = ((kk * 4 + kgl) ^ (n >> 2)) << 3;
        return *(const bf16x8*)&Bs[wv][p][n * LDT + go];
    };
    auto ldAf = [&](int s, int mi, int kk) -> bf16x8 {
        const int k = kbase + s * BK + kk * 32 + kgl * 8;
        const int r = m0 + mi * 16 + l16;
        const float* ap = ns + ((size_t)r * Usz + u) * Nsz + k;
        const f32x4 a0 = *(const f32x4*)ap;
        const f32x4 a1 = *(const f32x4*)(ap + 4);
        cell_u af;
        af.u[0] = pk(a0[0], a0[1]); af.u[1] = pk(a0[2], a0[3]);
        af.u[2] = pk(a1[0], a1[1]); af.u[3] = pk(a1[2], a1[3]);
        return af.b;
    };

    f32x4 acc[4][2] = {};
    auto comp = [&](int s, int p) {
        #pragma unroll
        for (int kk = 0; kk < 2; kk++) {
            const bf16x8 bf0 = rdB(p, 0, kk);
            const bf16x8 bf1 = rdB(p, 1, kk);
            #pragma unroll
            for (int mi = 0; mi < 4; mi++) {
                const bf16x8 af = ldAf(s, mi, kk);
                acc[mi][0] = __builtin_amdgcn_mfma_f32_16x16x32_bf16(af, bf0, acc[mi][0], 0, 0, 0);
                acc[mi][1] = __builtin_amdgcn_mfma_f32_16x16x32_bf16(af, bf1, acc[mi][1], 0, 0, 0);
            }
        }
    };

    ldB(0, rbE);
    ldB(1, rbO);
    wrB(0, rbE);

    for (int s2 = 0; s2 < nsteps / 2; s2++) {
        const int s = 2 * s2;
        if (s + 2 < nsteps) ldB(s + 2, rbE);
        wrB(1, rbO);
        comp(s, 0);
        if (s + 3 < nsteps) ldB(s + 3, rbO);
        if (s + 2 < nsteps) wrB(0, rbE);
        comp(s + 1, 1);
    }

    #pragma unroll
    for (int ni = 0; ni < 2; ni++) {
        const int gcol = col0 + ni * 16 + l16;
        #pragma unroll
        for (int mi = 0; mi < 4; mi++) {
            #pragma unroll
            for (int rg = 0; rg < 4; rg++) {
                const int grow = m0 + mi * 16 + kgl * 4 + rg;
                if (partial)
                    dst[(((size_t)ks * 16 + u) * 128 + grow) * 256 + gcol] = acc[mi][ni][rg];
                else
                    dst[((size_t)grow * Usz + u) * Osz + gcol] = acc[mi][ni][rg];
            }
        }
    }
}

// ---- sum 4 out-partials -> out1. 512 blocks x 256 thr ----
__global__ __launch_bounds__(256)
void out_reduce(const float* __restrict__ part, float* __restrict__ out1)
{
    const size_t i = (size_t)blockIdx.x * 256 + threadIdx.x;   // 0..131071
    const size_t base = i * 4;                 // flat [m][u][o]
    const int m = (int)(base >> 12);
    const int u = (int)((base >> 8) & 15);
    const int o = (int)(base & 255);

    const size_t pb = ((size_t)u * 128 + m) * 256 + o;
    const size_t slab = (size_t)16 * 128 * 256;
    f32x4 s = *(const f32x4*)(part + pb);
    s += *(const f32x4*)(part + pb + slab);
    s += *(const f32x4*)(part + pb + 2 * slab);
    s += *(const f32x4*)(part + pb + 3 * slab);
    *(f32x4*)(out1 + base) = s;
}

extern "C" void kernel_launch(void* const* d_in, const int* in_sizes, int n_in,
                              void* d_out, int out_size, void* d_ws, size_t ws_size,
                              hipStream_t stream)
{
    (void)in_sizes; (void)n_in; (void)out_size;
    const float* X     = (const float*)d_in[0];
    const float* state = (const float*)d_in[1];
    const float* W     = (const float*)d_in[2];
    const float* Win   = (const float*)d_in[3];
    const float* bias  = (const float*)d_in[4];
    const float* Wout  = (const float*)d_in[5];
    const float* sr    = (const float*)d_in[6];
    const float* alr   = (const float*)d_in[7];
    const float* temp  = (const float*)d_in[8];

    float* out0 = (float*)d_out;                      // (B,U,N)
    float* out1 = out0 + (size_t)Bsz * Usz * Nsz;     // (B,U,O)
    float* lr   = (float*)d_ws;                       // 8 KB

    const size_t p_off   = 8192;
    const size_t p_bytes = (size_t)4 * 16 * 128 * 256 * 4;   // 8 MiB

    lr_kernel<<<Bsz, 256, 0, stream>>>(X, alr, temp, lr);
    state_gemm<<<512, 128, 0, stream>>>(X, state, W, Win, bias, sr, lr, out0);

    if (ws_size >= p_off + p_bytes) {
        float* part = (float*)((char*)d_ws + p_off);
        out_gemm<<<512, 128, 0, stream>>>(out0, Wout, part, 4, 1);    // ks4
        out_reduce<<<512, 256, 0, stream>>>(part, out1);
    } else {
        out_gemm<<<128, 128, 0, stream>>>(out0, Wout, out1, 16, 0);   // ks1
    }
}

// Round 8
// 185.547 us; speedup vs baseline: 1.2192x; 1.2192x over previous
//
#include <hip/hip_runtime.h>
#include <math.h>

#define Bsz 128
#define Usz 16
#define Dsz 256
#define Nsz 1024
#define Osz 256
#define BK  64
#define LDT 72   // LDS row stride in u16 (144B)

typedef __attribute__((ext_vector_type(2))) unsigned int u32x2;
typedef __attribute__((ext_vector_type(4))) unsigned int u32x4;
typedef __attribute__((ext_vector_type(4))) float f32x4;
typedef __attribute__((ext_vector_type(8))) short bf16x8;

__device__ __forceinline__ unsigned int fbits(float f) {
    union { float f; unsigned int u; } v; v.f = f; return v.u;
}
// pack two f32 -> (bf16(hi)<<16)|bf16(lo) by truncation: 1 v_perm_b32
__device__ __forceinline__ unsigned int pk(float lo, float hi) {
    return __builtin_amdgcn_perm(fbits(hi), fbits(lo), 0x07060302u);
}
__device__ __forceinline__ unsigned short bf16t(float f) {
    return (unsigned short)(fbits(f) >> 16);
}

// Barrier WITHOUT the vmcnt(0) drain (v4-verified +18%). Un-clobbered asm
// (v3 lesson: "memory" clobber re-introduces the drain), sched_barrier fences.
__device__ __forceinline__ void sync_nodrain() {
    __builtin_amdgcn_sched_barrier(0);
    asm volatile("s_waitcnt lgkmcnt(0)");
    __builtin_amdgcn_sched_barrier(0);
    __builtin_amdgcn_s_barrier();
    __builtin_amdgcn_sched_barrier(0);
}

// ---------------- lr = softmax_u(X·alr / T) ----------------
__global__ __launch_bounds__(256)
void lr_kernel(const float* __restrict__ X, const float* __restrict__ alr,
               const float* __restrict__ temp, float* __restrict__ lr)
{
    const int b = blockIdx.x;
    const int t = threadIdx.x;
    const int u = t >> 4;
    const int l = t & 15;
    const f32x4* xp = (const f32x4*)(X + ((size_t)b * Usz + u) * Dsz + l * 16);
    const f32x4* ap = (const f32x4*)(alr + (size_t)u * Dsz + l * 16);
    float s = 0.f;
    #pragma unroll
    for (int j = 0; j < 4; j++) {
        const f32x4 xv = xp[j], av = ap[j];
        s += xv[0]*av[0] + xv[1]*av[1] + xv[2]*av[2] + xv[3]*av[3];
    }
    s += __shfl_down(s, 8, 16);
    s += __shfl_down(s, 4, 16);
    s += __shfl_down(s, 2, 16);
    s += __shfl_down(s, 1, 16);
    __shared__ float logits[16];
    if (l == 0) logits[u] = s;
    __syncthreads();
    if (t < 16) {
        const float T = temp[0];
        float m = -1e30f;
        #pragma unroll
        for (int i = 0; i < 16; i++) m = fmaxf(m, logits[i] / T);
        float sum = 0.f;
        #pragma unroll
        for (int i = 0; i < 16; i++) sum += expf(logits[i] / T - m);
        lr[(size_t)b * Usz + t] = expf(logits[t] / T - m) / sum;
    }
}

// ---- state GEMM v8: C = [X | state] · [Win ; sr*W], K=1280 ----
// 512-thread blocks (8 waves = wm4 x wn2), M=128 x N=32, grid 512 = u16 x
// nt32 -> 2 blocks/CU, 16 waves/CU (v6 concurrency) with B read ONCE
// chip-wide (v6's mt-split doubled FETCH 48->123MB; fixed here).
// Staging per thread per step: A 4x dwordx4 (64B contig), B 1x dwordx4;
// raw regs double-buffered at 1-full-step distance; pack->LDS next step.
// B transpose-store [n][k] with v7-verified XOR swizzle (write banks
// conflict-free; read b128). Nodrain barrier (v4 +18%). u inner in blockIdx
// -> each XCD sees only 2 distinct u -> W[u] L2-resident.
__global__ __launch_bounds__(512)
void state_gemm(const float* __restrict__ X, const float* __restrict__ state,
                const float* __restrict__ W, const float* __restrict__ Win,
                const float* __restrict__ bias, const float* __restrict__ sr,
                const float* __restrict__ lr, float* __restrict__ out0)
{
    const int id = blockIdx.x;        // 512 = nt32 x u16 (u inner)
    const int u  = id & 15;
    const int nt = id >> 4;

    const int tid  = threadIdx.x;     // 0..511
    const int wave = tid >> 6;        // 0..7
    const int lane = tid & 63;
    const int l16  = lane & 15, kgl = lane >> 4;
    const int wm = wave & 3, wn = wave >> 2;   // m-quarter (32 rows), n-half (16 cols)

    __shared__ unsigned short As[2][128 * LDT];  // 36.0 KB
    __shared__ unsigned short Bs[2][32 * LDT];   //  9.0 KB

    const float sru = sr[u];
    const int col0 = nt * 32;

    // A staging: thread -> row rA = tid>>2 (0..127), k-span cA..cA+15
    const int rA = tid >> 2;
    const int cA = (tid & 3) * 16;
    // B staging: thread -> k = kB (0..63), n = nB..nB+3
    // within wave w: kB = 8w + (lane>>3) -> k-group g = w (const), kL = lane>>3
    const int kB = tid >> 3;
    const int nB = (tid & 7) * 4;
    const int gB = kB >> 3, kL = kB & 7;

    f32x4 rAE[4], rAO[4];   // A raw double-buffer
    f32x4 rBE,    rBO;      // B raw double-buffer

    auto ldA = [&](int s, f32x4 (&ra)[4]) {
        const int k0 = s * BK;
        const float* base = (k0 < Dsz)
            ? X     + ((size_t)rA * Usz + u) * Dsz + k0 + cA
            : state + ((size_t)rA * Usz + u) * Nsz + (k0 - Dsz) + cA;
        #pragma unroll
        for (int j = 0; j < 4; j++) ra[j] = *(const f32x4*)(base + 4 * j);
    };
    auto ldB = [&](int s, f32x4& rb) {
        const int k0 = s * BK;
        const float* base = (k0 < Dsz)
            ? Win + (size_t)u * Dsz * Nsz + (size_t)(k0 + kB) * Nsz + col0 + nB
            : W   + (size_t)u * Nsz * Nsz + (size_t)(k0 - Dsz + kB) * Nsz + col0 + nB;
        rb = *(const f32x4*)base;
    };
    auto wrA = [&](int p, f32x4 (&ra)[4]) {
        u32x4 w0, w1;
        w0[0] = pk(ra[0][0], ra[0][1]); w0[1] = pk(ra[0][2], ra[0][3]);
        w0[2] = pk(ra[1][0], ra[1][1]); w0[3] = pk(ra[1][2], ra[1][3]);
        w1[0] = pk(ra[2][0], ra[2][1]); w1[1] = pk(ra[2][2], ra[2][3]);
        w1[2] = pk(ra[3][0], ra[3][1]); w1[3] = pk(ra[3][2], ra[3][3]);
        *(u32x4*)&As[p][rA * LDT + cA]     = w0;
        *(u32x4*)&As[p][rA * LDT + cA + 8] = w1;
    };
    // row n = nB+e (n>>2 == tid&7 == c), phys k-group = gB ^ c
    auto wrB = [&](int p, f32x4& rb, float sc) {
        const int c = tid & 7;
        const int go = ((gB ^ c) << 3) + kL;
        #pragma unroll
        for (int e = 0; e < 4; e++)
            Bs[p][(nB + e) * LDT + go] = bf16t(rb[e] * sc);
    };
    auto rdB = [&](int p, int kk) -> bf16x8 {
        const int n = wn * 16 + l16;
        const int go = (((kk * 4 + kgl) ^ (n >> 2)) << 3);
        return *(const bf16x8*)&Bs[p][n * LDT + go];
    };

    f32x4 acc[2] = {};
    auto comp = [&](int p) {
        #pragma unroll
        for (int kk = 0; kk < 2; kk++) {
            const bf16x8 bf = rdB(p, kk);
            #pragma unroll
            for (int mi = 0; mi < 2; mi++) {
                const bf16x8 af = *(const bf16x8*)&As[p][(wm * 32 + mi * 16 + l16) * LDT + kk * 32 + kgl * 8];
                acc[mi] = __builtin_amdgcn_mfma_f32_16x16x32_bf16(af, bf, acc[mi], 0, 0, 0);
            }
        }
    };
    auto scB = [&](int s) -> float { return (s * BK < Dsz) ? 1.f : sru; };

    // prologue: raw(0)->E, raw(1)->O, stage step0 into buf0
    ldA(0, rAE); ldB(0, rBE);
    ldA(1, rAO); ldB(1, rBO);
    wrA(0, rAE); wrB(0, rBE, scB(0));
    sync_nodrain();

    for (int s2 = 0; s2 < 10; s2++) {
        const int s = 2 * s2;
        // even: consume buf0(step s); stage s+1 (from O); prefetch raw s+2 -> E
        if (s + 2 < 20) { ldA(s + 2, rAE); ldB(s + 2, rBE); }
        wrA(1, rAO); wrB(1, rBO, scB(s + 1));
        comp(0);
        sync_nodrain();
        // odd: consume buf1(step s+1); stage s+2 (from E); prefetch raw s+3 -> O
        if (s + 3 < 20) { ldA(s + 3, rAO); ldB(s + 3, rBO); }
        if (s + 2 < 20) { wrA(0, rAE); wrB(0, rBE, scB(s + 2)); }
        comp(1);
        sync_nodrain();
    }

    // C/D layout: col=lane&15, row=(lane>>4)*4+reg (HW-verified)
    const int gcol = col0 + wn * 16 + l16;
    const float bi = bias[u * Nsz + gcol];
    #pragma unroll
    for (int mi = 0; mi < 2; mi++) {
        #pragma unroll
        for (int rg = 0; rg < 4; rg++) {
            const int grow = wm * 32 + mi * 16 + kgl * 4 + rg;
            const size_t idx = ((size_t)grow * Usz + u) * Nsz + gcol;
            const float th = tanhf(acc[mi][rg] + bi);
            const float lv = lr[grow * Usz + u];
            out0[idx] = (1.f - lv) * state[idx] + lv * th;
        }
    }
}

// ---- out GEMM v8: ns(128xK=1024) · Wout(Kx256), same structure, split-K ----
// grid = ks4 x u16 x ot8 = 512 blocks x 512 thr, M=128 x N=32, nsteps=4.
__global__ __launch_bounds__(512)
void out_gemm(const float* __restrict__ ns, const float* __restrict__ Wout,
              float* __restrict__ dst, int nsteps, int partial)
{
    const int id = blockIdx.x;
    const int ot = id & 7;
    const int u  = (id >> 3) & 15;
    const int ks = id >> 7;
    const int kbase = ks * nsteps * BK;

    const int tid  = threadIdx.x;
    const int wave = tid >> 6;
    const int lane = tid & 63;
    const int l16  = lane & 15, kgl = lane >> 4;
    const int wm = wave & 3, wn = wave >> 2;

    __shared__ unsigned short As[2][128 * LDT];
    __shared__ unsigned short Bs[2][32 * LDT];

    const int col0 = ot * 32;
    const int rA = tid >> 2;
    const int cA = (tid & 3) * 16;
    const int kB = tid >> 3;
    const int nB = (tid & 7) * 4;
    const int gB = kB >> 3, kL = kB & 7;

    f32x4 rAE[4], rAO[4];
    f32x4 rBE,    rBO;

    auto ldA = [&](int s, f32x4 (&ra)[4]) {
        const float* base = ns + ((size_t)rA * Usz + u) * Nsz + kbase + s * BK + cA;
        #pragma unroll
        for (int j = 0; j < 4; j++) ra[j] = *(const f32x4*)(base + 4 * j);
    };
    auto ldB = [&](int s, f32x4& rb) {
        rb = *(const f32x4*)(Wout + (size_t)u * Nsz * Osz
                             + (size_t)(kbase + s * BK + kB) * Osz + col0 + nB);
    };
    auto wrA = [&](int p, f32x4 (&ra)[4]) {
        u32x4 w0, w1;
        w0[0] = pk(ra[0][0], ra[0][1]); w0[1] = pk(ra[0][2], ra[0][3]);
        w0[2] = pk(ra[1][0], ra[1][1]); w0[3] = pk(ra[1][2], ra[1][3]);
        w1[0] = pk(ra[2][0], ra[2][1]); w1[1] = pk(ra[2][2], ra[2][3]);
        w1[2] = pk(ra[3][0], ra[3][1]); w1[3] = pk(ra[3][2], ra[3][3]);
        *(u32x4*)&As[p][rA * LDT + cA]     = w0;
        *(u32x4*)&As[p][rA * LDT + cA + 8] = w1;
    };
    auto wrB = [&](int p, f32x4& rb) {
        const int c = tid & 7;
        const int go = ((gB ^ c) << 3) + kL;
        #pragma unroll
        for (int e = 0; e < 4; e++)
            Bs[p][(nB + e) * LDT + go] = bf16t(rb[e]);
    };
    auto rdB = [&](int p, int kk) -> bf16x8 {
        const int n = wn * 16 + l16;
        const int go = (((kk * 4 + kgl) ^ (n >> 2)) << 3);
        return *(const bf16x8*)&Bs[p][n * LDT + go];
    };

    f32x4 acc[2] = {};
    auto comp = [&](int p) {
        #pragma unroll
        for (int kk = 0; kk < 2; kk++) {
            const bf16x8 bf = rdB(p, kk);
            #pragma unroll
            for (int mi = 0; mi < 2; mi++) {
                const bf16x8 af = *(const bf16x8*)&As[p][(wm * 32 + mi * 16 + l16) * LDT + kk * 32 + kgl * 8];
                acc[mi] = __builtin_amdgcn_mfma_f32_16x16x32_bf16(af, bf, acc[mi], 0, 0, 0);
            }
        }
    };

    ldA(0, rAE); ldB(0, rBE);
    ldA(1, rAO); ldB(1, rBO);
    wrA(0, rAE); wrB(0, rBE);
    sync_nodrain();

    for (int s2 = 0; s2 < nsteps / 2; s2++) {
        const int s = 2 * s2;
        if (s + 2 < nsteps) { ldA(s + 2, rAE); ldB(s + 2, rBE); }
        wrA(1, rAO); wrB(1, rBO);
        comp(0);
        sync_nodrain();
        if (s + 3 < nsteps) { ldA(s + 3, rAO); ldB(s + 3, rBO); }
        if (s + 2 < nsteps) { wrA(0, rAE); wrB(0, rBE); }
        comp(1);
        sync_nodrain();
    }

    const int gcol = col0 + wn * 16 + l16;
    #pragma unroll
    for (int mi = 0; mi < 2; mi++) {
        #pragma unroll
        for (int rg = 0; rg < 4; rg++) {
            const int grow = wm * 32 + mi * 16 + kgl * 4 + rg;
            if (partial)
                dst[(((size_t)ks * 16 + u) * 128 + grow) * 256 + gcol] = acc[mi][rg];
            else
                dst[((size_t)grow * Usz + u) * Osz + gcol] = acc[mi][rg];
        }
    }
}

// ---- sum 4 out-partials -> out1. 512 blocks x 256 thr ----
__global__ __launch_bounds__(256)
void out_reduce(const float* __restrict__ part, float* __restrict__ out1)
{
    const size_t i = (size_t)blockIdx.x * 256 + threadIdx.x;   // 0..131071
    const size_t base = i * 4;                 // flat [m][u][o]
    const int m = (int)(base >> 12);
    const int u = (int)((base >> 8) & 15);
    const int o = (int)(base & 255);

    const size_t pb = ((size_t)u * 128 + m) * 256 + o;
    const size_t slab = (size_t)16 * 128 * 256;
    f32x4 s = *(const f32x4*)(part + pb);
    s += *(const f32x4*)(part + pb + slab);
    s += *(const f32x4*)(part + pb + 2 * slab);
    s += *(const f32x4*)(part + pb + 3 * slab);
    *(f32x4*)(out1 + base) = s;
}

extern "C" void kernel_launch(void* const* d_in, const int* in_sizes, int n_in,
                              void* d_out, int out_size, void* d_ws, size_t ws_size,
                              hipStream_t stream)
{
    (void)in_sizes; (void)n_in; (void)out_size;
    const float* X     = (const float*)d_in[0];
    const float* state = (const float*)d_in[1];
    const float* W     = (const float*)d_in[2];
    const float* Win   = (const float*)d_in[3];
    const float* bias  = (const float*)d_in[4];
    const float* Wout  = (const float*)d_in[5];
    const float* sr    = (const float*)d_in[6];
    const float* alr   = (const float*)d_in[7];
    const float* temp  = (const float*)d_in[8];

    float* out0 = (float*)d_out;                      // (B,U,N)
    float* out1 = out0 + (size_t)Bsz * Usz * Nsz;     // (B,U,O)
    float* lr   = (float*)d_ws;                       // 8 KB

    const size_t p_off   = 8192;
    const size_t p_bytes = (size_t)4 * 16 * 128 * 256 * 4;   // 8 MiB

    lr_kernel<<<Bsz, 256, 0, stream>>>(X, alr, temp, lr);
    state_gemm<<<512, 512, 0, stream>>>(X, state, W, Win, bias, sr, lr, out0);

    if (ws_size >= p_off + p_bytes) {
        float* part = (float*)((char*)d_ws + p_off);
        out_gemm<<<512, 512, 0, stream>>>(out0, Wout, part, 4, 1);    // ks4
        out_reduce<<<512, 256, 0, stream>>>(part, out1);
    } else {
        out_gemm<<<128, 512, 0, stream>>>(out0, Wout, out1, 16, 0);   // ks1
    }
}